// Round 1
// baseline (57.536 us; speedup 1.0000x reference)
//
#include <hip/hip_runtime.h>
#include <math.h>

// Problem constants (match reference: x is [L][B] float32, row-major).
constexpr int L = 8192;
constexpr int B = 4096;
constexpr int CH = 64;            // rows per chunk
constexpr int NC = L / CH;        // 128 chunks
constexpr int TPB = 256;          // threads per block
constexpr int VEC = 4;            // columns per thread (float4)
constexpr int COLS_PER_BLOCK = TPB * VEC;   // 1024
constexpr int COL_TILES = B / COLS_PER_BLOCK; // 4

__device__ __forceinline__ float fast_sigmoid(float t) {
    // 1/(1+exp(-t)); v_exp_f32 + v_rcp_f32. Plenty accurate for this tolerance.
    return __builtin_amdgcn_rcpf(1.0f + __expf(-t));
}

// Pass 1: per-chunk, per-column max of raw x (sigmoid is monotonic, so we can
// defer it). cmax[c][b] = max over rows in chunk c of x[row][b].
__global__ __launch_bounds__(TPB) void soft_len_chunk_max(
        const float* __restrict__ x, float* __restrict__ cmax) {
    const int chunk = blockIdx.x;
    const int col = blockIdx.y * COLS_PER_BLOCK + threadIdx.x * VEC;
    const float4* xin =
        reinterpret_cast<const float4*>(x + (size_t)chunk * CH * B + col);
    float4 m = make_float4(-INFINITY, -INFINITY, -INFINITY, -INFINITY);
    #pragma unroll 8
    for (int r = 0; r < CH; ++r) {
        float4 v = xin[(size_t)r * (B / VEC)];
        m.x = fmaxf(m.x, v.x);
        m.y = fmaxf(m.y, v.y);
        m.z = fmaxf(m.z, v.z);
        m.w = fmaxf(m.w, v.w);
    }
    *reinterpret_cast<float4*>(cmax + (size_t)chunk * B + col) = m;
}

// Pass 2: in-place EXCLUSIVE suffix max across chunks, per column.
// After this, cmax[c][b] = max over chunks c' > c of original cmax[c'][b].
__global__ __launch_bounds__(TPB) void soft_len_suffix_max(
        float* __restrict__ cmax) {
    const int col = blockIdx.x * TPB + threadIdx.x; // one column per thread
    float run = -INFINITY;
    #pragma unroll 8
    for (int c = NC - 1; c >= 0; --c) {
        float v = cmax[(size_t)c * B + col];
        cmax[(size_t)c * B + col] = run;   // exclusive suffix
        run = fmaxf(run, v);
    }
}

// Pass 3: re-read chunk (L3-warm), reverse running max seeded with the carry,
// accumulate sigmoid(tail) per element. partial[c][b] = chunk's contribution.
__global__ __launch_bounds__(TPB) void soft_len_chunk_scan(
        const float* __restrict__ x, const float* __restrict__ carry,
        float* __restrict__ partial) {
    const int chunk = blockIdx.x;
    const int col = blockIdx.y * COLS_PER_BLOCK + threadIdx.x * VEC;
    const float4* xin =
        reinterpret_cast<const float4*>(x + (size_t)chunk * CH * B + col);
    float4 tail = *reinterpret_cast<const float4*>(carry + (size_t)chunk * B + col);
    float4 sum = make_float4(0.f, 0.f, 0.f, 0.f);
    #pragma unroll 8
    for (int r = CH - 1; r >= 0; --r) {
        float4 v = xin[(size_t)r * (B / VEC)];
        tail.x = fmaxf(tail.x, v.x);
        tail.y = fmaxf(tail.y, v.y);
        tail.z = fmaxf(tail.z, v.z);
        tail.w = fmaxf(tail.w, v.w);
        sum.x += fast_sigmoid(tail.x);
        sum.y += fast_sigmoid(tail.y);
        sum.z += fast_sigmoid(tail.z);
        sum.w += fast_sigmoid(tail.w);
    }
    *reinterpret_cast<float4*>(partial + (size_t)chunk * B + col) = sum;
}

// Pass 4: out[b] = sum over chunks of partial[c][b].
__global__ __launch_bounds__(TPB) void soft_len_reduce(
        const float* __restrict__ partial, float* __restrict__ out) {
    const int col = blockIdx.x * TPB + threadIdx.x;
    float s = 0.f;
    #pragma unroll 8
    for (int c = 0; c < NC; ++c) s += partial[(size_t)c * B + col];
    out[col] = s;
}

extern "C" void kernel_launch(void* const* d_in, const int* in_sizes, int n_in,
                              void* d_out, int out_size, void* d_ws, size_t ws_size,
                              hipStream_t stream) {
    const float* x = (const float*)d_in[0];
    float* out = (float*)d_out;

    // Workspace layout: cmax/carry [NC][B] (2 MiB), partial [NC][B] (2 MiB).
    float* cmax = (float*)d_ws;
    float* partial = cmax + (size_t)NC * B;

    dim3 gbig(NC, COL_TILES);  // (128, 4) = 512 blocks
    soft_len_chunk_max<<<gbig, TPB, 0, stream>>>(x, cmax);
    soft_len_suffix_max<<<B / TPB, TPB, 0, stream>>>(cmax);
    soft_len_chunk_scan<<<gbig, TPB, 0, stream>>>(x, cmax, partial);
    soft_len_reduce<<<B / TPB, TPB, 0, stream>>>(partial, out);
}